// Round 9
// baseline (323.163 us; speedup 1.0000x reference)
//
#include <hip/hip_runtime.h>

#define FEAT 128
#define SLABS 4

typedef __attribute__((ext_vector_type(8))) _Float16 f16x8;
typedef __attribute__((ext_vector_type(2))) _Float16 f16x2;
typedef __attribute__((ext_vector_type(4))) float f32x4;

static __device__ __forceinline__ int wave_incl_scan(int v, int lane) {
#pragma unroll
    for (int off = 1; off < 64; off <<= 1) {
        int u = __shfl_up(v, off, 64);
        if (lane >= off) v += u;
    }
    return v;
}

// ---------------------------------------------------------------------------
// Prep: histogram over (dst,slab) keys + weight/bias/feat converts, one
// dispatch partitioned by blockIdx. atomicAdd return = edge rank in bucket
// -> erank (atomic-free scatter later).
// ---------------------------------------------------------------------------

__global__ void prep_kernel(const int* __restrict__ src, const int* __restrict__ dst,
                            int* __restrict__ deg4, int* __restrict__ erank,
                            int E, int slab_size,
                            const float* __restrict__ tw, const float* __restrict__ pw,
                            const float* __restrict__ tb, const float* __restrict__ pb,
                            _Float16* __restrict__ wt, _Float16* __restrict__ wp,
                            float* __restrict__ bsum, int wn, int nbias,
                            const float* __restrict__ x, _Float16* __restrict__ x16, int xn4,
                            int hb, int wb) {
    int bid = blockIdx.x;
    if (bid < hb) {
        int e = bid * 256 + threadIdx.x;
        if (e < E) {
            int sl = src[e] / slab_size;
            erank[e] = atomicAdd(&deg4[dst[e] * SLABS + sl], 1);
        }
    } else if (bid < hb + wb) {
        int i = (bid - hb) * 256 + threadIdx.x;
        if (i < wn) { wt[i] = (_Float16)tw[i]; wp[i] = (_Float16)pw[i]; }
        if (i < nbias) bsum[i] = tb[i] + pb[i];
    } else {
        int i = (bid - hb - wb) * 256 + threadIdx.x;
        if (i < xn4) {
            float4 v = ((const float4*)x)[i];
            f16x2 a, b;
            a[0] = (_Float16)v.x; a[1] = (_Float16)v.y;
            b[0] = (_Float16)v.z; b[1] = (_Float16)v.w;
            ((f16x2*)x16)[i * 2] = a;
            ((f16x2*)x16)[i * 2 + 1] = b;
        }
    }
}

// ---------------------------------------------------------------------------
// 2-dispatch scan (scan3 folded into consumers: they add boff[idx>>10]).
// Round-5 lesson: NO single-dispatch device-scope-spin scan (cost 103 us).
// ---------------------------------------------------------------------------

__global__ __launch_bounds__(1024) void scan1_kernel(const int* __restrict__ deg,
                                                     int* __restrict__ row_ptr,
                                                     int* __restrict__ bsum, int N4) {
    int i = blockIdx.x * 1024 + threadIdx.x;
    int lane = threadIdx.x & 63;
    int w = threadIdx.x >> 6;
    int v = (i < N4) ? deg[i] : 0;
    int inc = wave_incl_scan(v, lane);
    __shared__ int wsum[16];
    if (lane == 63) wsum[w] = inc;
    __syncthreads();
    if (w == 0) {
        int s = (lane < 16) ? wsum[lane] : 0;
        int si = wave_incl_scan(s, lane);
        if (lane < 16) wsum[lane] = si - s;
    }
    __syncthreads();
    int exc = inc - v + wsum[w];
    if (i < N4) row_ptr[i] = exc;
    if (threadIdx.x == 1023) bsum[blockIdx.x] = exc + v;
}

// boff[tid] for tid<=nb; sentinel row_ptr[N4] pre-compensated so that
// consumers can uniformly compute row_ptr[idx] + boff[idx>>10].
__global__ __launch_bounds__(1024) void scan2_kernel(const int* __restrict__ bsum,
                                                     int* __restrict__ boff,
                                                     int* __restrict__ row_ptr,
                                                     int nb, int N4, int E) {
    int tid = threadIdx.x;
    int lane = tid & 63;
    int w = tid >> 6;
    int v = (tid < nb) ? bsum[tid] : 0;
    int inc = wave_incl_scan(v, lane);
    __shared__ int wsum[16];
    if (lane == 63) wsum[w] = inc;
    __syncthreads();
    if (w == 0) {
        int s = (lane < 16) ? wsum[lane] : 0;
        int si = wave_incl_scan(s, lane);
        if (lane < 16) wsum[lane] = si - s;
    }
    __syncthreads();
    int b = inc - v + wsum[w];
    if (tid <= nb) boff[tid] = b;
    if (tid == (N4 >> 10)) row_ptr[N4] = E - b;   // + boff[N4>>10] == E
}

// ---------------------------------------------------------------------------
// Fused MFMA GEMM body (verified): t = x @ Wt.T, q = x @ Wp.T - t + (tb+pb).
// C/D layout: col = lane&15, row = (lane>>4)*4+reg.
// ---------------------------------------------------------------------------

static __device__ __forceinline__ void gemm_body(
        int bx, int nslab,
        const _Float16* __restrict__ x16,
        const _Float16* __restrict__ wt, const _Float16* __restrict__ wp,
        const float* __restrict__ bias,
        _Float16* __restrict__ t16, _Float16* __restrict__ q16, int M) {
    int lane = threadIdx.x & 63;
    int l16 = lane & 15;
    int quad = lane >> 4;
    int cn0 = (threadIdx.x >> 6) * 32;

    f16x8 bt[2][4], bp[2][4];
    float biasv[2];
#pragma unroll
    for (int ct = 0; ct < 2; ++ct) {
        int col = cn0 + ct * 16 + l16;
        biasv[ct] = bias[col];
#pragma unroll
        for (int kk = 0; kk < 4; ++kk) {
            int k = kk * 32 + quad * 8;
            bt[ct][kk] = *(const f16x8*)(wt + (size_t)col * FEAT + k);
            bp[ct][kk] = *(const f16x8*)(wp + (size_t)col * FEAT + k);
        }
    }

    int rbase0 = bx * (nslab * 16);
#pragma unroll 1
    for (int rs = 0; rs < nslab; ++rs) {
        int rbase = rbase0 + rs * 16;
        int row = rbase + l16;
        int rowc = (row < M) ? row : (M - 1);
        f16x8 a[4];
#pragma unroll
        for (int kk = 0; kk < 4; ++kk)
            a[kk] = *(const f16x8*)(x16 + (size_t)rowc * FEAT + kk * 32 + quad * 8);

        f32x4 accT[2] = {{0.f, 0.f, 0.f, 0.f}, {0.f, 0.f, 0.f, 0.f}};
        f32x4 accP[2] = {{0.f, 0.f, 0.f, 0.f}, {0.f, 0.f, 0.f, 0.f}};
#pragma unroll
        for (int kk = 0; kk < 4; ++kk) {
#pragma unroll
            for (int ct = 0; ct < 2; ++ct) {
                accT[ct] = __builtin_amdgcn_mfma_f32_16x16x32_f16(a[kk], bt[ct][kk], accT[ct], 0, 0, 0);
                accP[ct] = __builtin_amdgcn_mfma_f32_16x16x32_f16(a[kk], bp[ct][kk], accP[ct], 0, 0, 0);
            }
        }
#pragma unroll
        for (int ct = 0; ct < 2; ++ct) {
            int col = cn0 + ct * 16 + l16;
#pragma unroll
            for (int r = 0; r < 4; ++r) {
                int ro = rbase + quad * 4 + r;
                if (ro < M) {
                    t16[(size_t)ro * FEAT + col] = (_Float16)accT[ct][r];
                    q16[(size_t)ro * FEAT + col] =
                        (_Float16)(accP[ct][r] - accT[ct][r] + biasv[ct]);
                }
            }
        }
    }
}

// Layer-0 GEMM fused with the atomic-free CSR scatter.
__global__ __launch_bounds__(256) void fused0_kernel(
        const _Float16* __restrict__ x16,
        const _Float16* __restrict__ wt, const _Float16* __restrict__ wp,
        const float* __restrict__ bias,
        _Float16* __restrict__ t16, _Float16* __restrict__ q16, int M, int gb,
        const int* __restrict__ src, const int* __restrict__ dst,
        const int* __restrict__ row_ptr4, const int* __restrict__ boff,
        const int* __restrict__ erank,
        int* __restrict__ esrc, int E, int slab_size) {
    if ((int)blockIdx.x < gb) {
        gemm_body(blockIdx.x, 8, x16, wt, wp, bias, t16, q16, M);
    } else {
        int e = (blockIdx.x - gb) * 256 + threadIdx.x;
        if (e < E) {
            int s = src[e];
            int key = dst[e] * SLABS + s / slab_size;
            esrc[row_ptr4[key] + boff[key >> 10] + erank[e]] = s;
        }
    }
}

// ---------------------------------------------------------------------------
// Gather-max core (round-1 verified, the only agg structure that never
// regressed). Wave handles one node; slot g = edge sub-slot, c = feature
// chunk. Returns the cross-slot-reduced f16x8 max.
// ---------------------------------------------------------------------------

static __device__ __forceinline__ f16x8 vmax8(f16x8 a, f16x8 b) {
#pragma unroll
    for (int i = 0; i < 8; ++i) a[i] = (a[i] > b[i]) ? a[i] : b[i];
    return a;
}

static __device__ __forceinline__ f16x8 shfl_xor8(f16x8 v, int m) {
    union { f16x8 h; int i[4]; } u, r;
    u.h = v;
#pragma unroll
    for (int d = 0; d < 4; ++d) r.i[d] = __shfl_xor(u.i[d], m, 64);
    return r.h;
}

static __device__ __forceinline__ f16x8 gather_max(
        const _Float16* __restrict__ t16, const int* __restrict__ esrc,
        int beg, int cnt, int lane, int g, int c) {
    const _Float16 NEGINF = (_Float16)(-65504.0f);
    f16x8 m0, m1;
#pragma unroll
    for (int i = 0; i < 8; ++i) { m0[i] = NEGINF; m1[i] = NEGINF; }

    for (int cb = 0; cb < cnt; cb += 64) {
        int lim = cnt - cb; if (lim > 64) lim = 64;
        int a = beg + cb + (lane < lim ? lane : 0);
        int myidx = esrc[a];                    // one coalesced index load
        for (int base = 0; base < lim; base += 8) {
            int e0 = base + g;     if (e0 >= lim) e0 = 0;
            int e1 = base + 4 + g; if (e1 >= lim) e1 = 0;
            int i0 = __shfl(myidx, e0, 64);
            int i1 = __shfl(myidx, e1, 64);
            f16x8 v0 = *(const f16x8*)(t16 + (size_t)i0 * FEAT + c * 8);
            f16x8 v1 = *(const f16x8*)(t16 + (size_t)i1 * FEAT + c * 8);
            m0 = vmax8(m0, v0);
            m1 = vmax8(m1, v1);
        }
    }

    f16x8 mm = vmax8(m0, m1);
    mm = vmax8(mm, shfl_xor8(mm, 16));
    mm = vmax8(mm, shfl_xor8(mm, 32));
    return mm;
}

// lane (g,c) owns features {c*8+2g, c*8+2g+1}: static select of dword g.
static __device__ __forceinline__ f16x2 slot_pair(f16x8 mm, int g) {
    union { f16x8 h; int i[4]; } um; um.h = mm;
    int w01 = (g & 1) ? um.i[1] : um.i[0];
    int w23 = (g & 1) ? um.i[3] : um.i[2];
    int w = (g & 2) ? w23 : w01;
    union { int i; f16x2 h; } uw; uw.i = w;
    return uw.h;
}

// ---------------------------------------------------------------------------
// Fused agg(layer l) + GEMM(layer l+1), 1024 threads / 16 waves per block.
// Round-8 lesson: the 256-thread version serialized 4 nodes per wave ->
// 12.5k waves total (vs 50k standalone) -> latency-bound at 52.8 us
// (VALUBusy 46%, HBM 24%, MfmaUtil 2%). This version restores WAVE-PER-NODE
// (phase 1: wave wv aggs node0+wv, 50k waves) and keeps the fusion: x_next
// goes through a 4 KB XOR-swizzled LDS tile; barrier; phase 2: waves 0-7
// each own one 16-col tile (4+4 MFMA for accT/accP), waves 8-15 idle
// through the short GEMM tail. VGPR 28 -> 2 blocks/CU = 32 waves/CU.
// ---------------------------------------------------------------------------

__global__ __launch_bounds__(1024) void fusedagg_kernel(
        const _Float16* __restrict__ t16, const _Float16* __restrict__ q16,
        const int* __restrict__ row_ptr4, const int* __restrict__ boff,
        const int* __restrict__ esrc,
        const _Float16* __restrict__ wt, const _Float16* __restrict__ wp,
        const float* __restrict__ bias,
        _Float16* __restrict__ tn, _Float16* __restrict__ qn, int N) {
    __shared__ _Float16 xl[16 * FEAT];
    int wv = threadIdx.x >> 6;     // 0..15: one node per wave
    int lane = threadIdx.x & 63;
    int g = lane >> 4;
    int c = lane & 15;
    int node0 = blockIdx.x * 16;

    // phase 1: wave wv aggregates node node0+wv
    {
        int node = node0 + wv;
        float o0 = 0.f, o1 = 0.f;
        if (node < N) {
            int bi = node * SLABS;
            int beg = row_ptr4[bi] + boff[bi >> 10];
            int end = row_ptr4[bi + SLABS] + boff[(bi + SLABS) >> 10];
            f16x2 qv = *(const f16x2*)(q16 + (size_t)node * FEAT + c * 8 + g * 2);
            f16x8 mm = gather_max(t16, esrc, beg, end - beg, lane, g, c);
            f16x2 mp = slot_pair(mm, g);
            o0 = fmaxf((float)mp[0] + (float)qv[0], 0.f);
            o1 = fmaxf((float)mp[1] + (float)qv[1], 0.f);
        }
        f16x2 oh; oh[0] = (_Float16)o0; oh[1] = (_Float16)o1;
        int byteoff = (wv * 256 + c * 16 + g * 4) ^ ((wv & 7) << 4);
        *(f16x2*)((char*)xl + byteoff) = oh;
    }
    __syncthreads();

    // phase 2: waves 0-7, wave wv owns cols wv*16..wv*16+15 (both T and P).
    if (wv < 8) {
        int l16 = lane & 15;
        int quad = lane >> 4;
        f16x8 a[4];
#pragma unroll
        for (int kk = 0; kk < 4; ++kk) {
            int byteoff = (l16 * 256 + kk * 64 + quad * 16) ^ ((l16 & 7) << 4);
            a[kk] = *(const f16x8*)((const char*)xl + byteoff);
        }
        int col = wv * 16 + l16;
        float bv = bias[col];
        f16x8 fb[4];
#pragma unroll
        for (int kk = 0; kk < 4; ++kk)
            fb[kk] = *(const f16x8*)(wt + (size_t)col * FEAT + kk * 32 + quad * 8);
        f32x4 accT = {0.f, 0.f, 0.f, 0.f};
#pragma unroll
        for (int kk = 0; kk < 4; ++kk)
            accT = __builtin_amdgcn_mfma_f32_16x16x32_f16(a[kk], fb[kk], accT, 0, 0, 0);
#pragma unroll
        for (int kk = 0; kk < 4; ++kk)
            fb[kk] = *(const f16x8*)(wp + (size_t)col * FEAT + kk * 32 + quad * 8);
        f32x4 accP = {0.f, 0.f, 0.f, 0.f};
#pragma unroll
        for (int kk = 0; kk < 4; ++kk)
            accP = __builtin_amdgcn_mfma_f32_16x16x32_f16(a[kk], fb[kk], accP, 0, 0, 0);
#pragma unroll
        for (int r = 0; r < 4; ++r) {
            int ro = node0 + quad * 4 + r;
            if (ro < N) {
                tn[(size_t)ro * FEAT + col] = (_Float16)accT[r];
                qn[(size_t)ro * FEAT + col] = (_Float16)(accP[r] - accT[r] + bv);
            }
        }
    }
}

// Final-layer agg: full-occupancy standalone (biggest single consumer),
// writes fp32 d_out.
__global__ __launch_bounds__(256) void agg_kernel(
        const _Float16* __restrict__ t16, const _Float16* __restrict__ q16,
        const int* __restrict__ row_ptr4, const int* __restrict__ boff,
        const int* __restrict__ esrc,
        float* __restrict__ outf, int N) {
    int wv = threadIdx.x >> 6;
    int lane = threadIdx.x & 63;
    int node = blockIdx.x * 4 + wv;
    if (node >= N) return;

    int g = lane >> 4;
    int c = lane & 15;

    int bi = node * SLABS;
    int beg = row_ptr4[bi] + boff[bi >> 10];
    int end = row_ptr4[bi + SLABS] + boff[(bi + SLABS) >> 10];

    f16x2 qv = *(const f16x2*)(q16 + (size_t)node * FEAT + c * 8 + g * 2);
    f16x8 mm = gather_max(t16, esrc, beg, end - beg, lane, g, c);
    f16x2 mp = slot_pair(mm, g);

    float o0 = fmaxf((float)mp[0] + (float)qv[0], 0.f);
    float o1 = fmaxf((float)mp[1] + (float)qv[1], 0.f);
    float2 ov = make_float2(o0, o1);
    *(float2*)(outf + (size_t)node * FEAT + c * 8 + g * 2) = ov;
}

// ---------------------------------------------------------------------------

extern "C" void kernel_launch(void* const* d_in, const int* in_sizes, int n_in,
                              void* d_out, int out_size, void* d_ws, size_t ws_size,
                              hipStream_t stream) {
    const float* feats   = (const float*)d_in[0];
    const int*   src     = (const int*)d_in[1];
    const int*   dst     = (const int*)d_in[2];
    const float* theta_w = (const float*)d_in[3];
    const float* theta_b = (const float*)d_in[4];
    const float* phi_w   = (const float*)d_in[5];
    const float* phi_b   = (const float*)d_in[6];

    const int N = in_sizes[0] / FEAT;
    const int E = in_sizes[1];
    const int L = in_sizes[3] / (FEAT * FEAT);
    const int N4 = N * SLABS;
    const int slab_size = (N + SLABS - 1) / SLABS;

    char* ws = (char*)d_ws;
    size_t off = 0;
    auto alloc = [&](size_t bytes) -> void* {
        void* ptr = ws + off;
        off = (off + bytes + 255) & ~(size_t)255;
        return ptr;
    };
    _Float16* tbuf[2];
    _Float16* qbuf[2];
    tbuf[0] = (_Float16*)alloc((size_t)N * FEAT * 2);
    tbuf[1] = (_Float16*)alloc((size_t)N * FEAT * 2);
    qbuf[0] = (_Float16*)alloc((size_t)N * FEAT * 2);
    qbuf[1] = (_Float16*)alloc((size_t)N * FEAT * 2);
    _Float16* x16 = (_Float16*)alloc((size_t)N * FEAT * 2);
    _Float16* wt16 = (_Float16*)alloc((size_t)L * FEAT * FEAT * 2);
    _Float16* wp16 = (_Float16*)alloc((size_t)L * FEAT * FEAT * 2);
    float* bsum_b = (float*)alloc((size_t)L * FEAT * sizeof(float));
    int* deg4     = (int*)alloc((size_t)N4 * sizeof(int));
    int* row_ptr4 = (int*)alloc((size_t)(N4 + 1) * sizeof(int));
    int* erank    = (int*)alloc((size_t)E * sizeof(int));
    int* esrc     = (int*)alloc((size_t)E * sizeof(int));
    int* bsum     = (int*)alloc(2048 * sizeof(int));
    int* boff     = (int*)alloc(2048 * sizeof(int));
    (void)ws_size;

    hipMemsetAsync(deg4, 0, (size_t)N4 * sizeof(int), stream);

    int eb = (E + 255) / 256;
    int wn = L * FEAT * FEAT;
    int wb = (wn + 255) / 256;
    int xn4 = N * FEAT / 4;
    int xb = (xn4 + 255) / 256;
    prep_kernel<<<eb + wb + xb, 256, 0, stream>>>(
        src, dst, deg4, erank, E, slab_size,
        theta_w, phi_w, theta_b, phi_b, wt16, wp16, bsum_b, wn, L * FEAT,
        feats, x16, xn4, eb, wb);

    int nb = (N4 + 1023) >> 10;
    scan1_kernel<<<nb, 1024, 0, stream>>>(deg4, row_ptr4, bsum, N4);
    scan2_kernel<<<1, 1024, 0, stream>>>(bsum, boff, row_ptr4, nb, N4, E);

    int gb = (N + 127) / 128;
    fused0_kernel<<<gb + eb, 256, 0, stream>>>(
        x16, wt16, wp16, bsum_b, tbuf[0], qbuf[0], N, gb,
        src, dst, row_ptr4, boff, erank, esrc, E, slab_size);

    int fb = (N + 15) / 16;   // fusedagg: 16 nodes/block, wave-per-node
    for (int l = 0; l + 1 < L; ++l) {
        fusedagg_kernel<<<fb, 1024, 0, stream>>>(
            tbuf[l & 1], qbuf[l & 1], row_ptr4, boff, esrc,
            wt16 + (size_t)(l + 1) * FEAT * FEAT,
            wp16 + (size_t)(l + 1) * FEAT * FEAT,
            bsum_b + (size_t)(l + 1) * FEAT,
            tbuf[(l + 1) & 1], qbuf[(l + 1) & 1], N);
    }

    int ab = (N + 3) / 4;
    agg_kernel<<<ab, 256, 0, stream>>>(
        tbuf[(L - 1) & 1], qbuf[(L - 1) & 1], row_ptr4, boff, esrc,
        (float*)d_out, N);
}